// Round 2
// baseline (2830.764 us; speedup 1.0000x reference)
//
#include <hip/hip_runtime.h>
#include <hip/hip_bf16.h>
#include <math.h>

#define B_SZ    32
#define LSEQ    1024
#define DIN     128
#define HDIM    256
#define NLAYERS 4
#define NSTATE  32
#define DOUT    10
#define M_ROWS  (B_SZ*LSEQ)   // 32768

// ---------------- per-(layer,h,n) discretized params ----------------
// PW[idx] = (dtA_re, dtA_im / 2pi, W_re, W_im) where W = C * dB (complex)
__global__ void k_params(const float* __restrict__ log_dt, const float* __restrict__ A_re_log,
                         const float* __restrict__ A_im, const float* __restrict__ B_re,
                         const float* __restrict__ B_im, const float* __restrict__ C_re,
                         const float* __restrict__ C_im, float4* __restrict__ PW) {
    int idx = blockIdx.x * 256 + threadIdx.x;       // [0, NLAYERS*HDIM*NSTATE)
    int hn = idx >> 5;                              // layer*HDIM + h
    float dt   = expf(log_dt[hn]);
    float Are  = -expf(A_re_log[idx]);
    float Aim  = A_im[idx];
    float dtAre = dt * Are, dtAim = dt * Aim;
    float ea   = expf(dtAre);
    float dAre = ea * cosf(dtAim), dAim = ea * sinf(dtAim);
    float nre = dAre - 1.0f, nim = dAim;            // dA - 1
    float inv = 1.0f / (Are * Are + Aim * Aim);
    float tre = (nre * Are + nim * Aim) * inv;      // (dA-1)/A
    float tim = (nim * Are - nre * Aim) * inv;
    float Brv = B_re[idx], Biv = B_im[idx];
    float dBre = Brv * tre - Biv * tim;
    float dBim = Brv * tim + Biv * tre;
    float Crv = C_re[idx], Civ = C_im[idx];
    float Wre = Crv * dBre - Civ * dBim;
    float Wim = Crv * dBim + Civ * dBre;
    PW[idx] = make_float4(dtAre, dtAim * 0.15915494309189535f, Wre, Wim);
}

// ---------------- Vandermonde kernel K_t[layer][l][h] ----------------
__global__ void k_kern(const float4* __restrict__ PW, float* __restrict__ Kt) {
    int t = blockIdx.x * 256 + threadIdx.x;         // layer*L*H + l*H + h
    int h = t & (HDIM - 1);
    int l = (t >> 8) & (LSEQ - 1);
    int layer = t >> 18;
    const float4* p = PW + (layer * HDIM + h) * NSTATE;
    float fl = (float)l;
    float acc = 0.f;
#pragma unroll
    for (int n = 0; n < NSTATE; ++n) {
        float4 q = p[n];
        double ph = (double)q.y * (double)l;        // phase in revolutions, fp64 for range
        float th = (float)(ph - floor(ph)) * 6.283185307179586f;
        float mag = __expf(q.x * fl);
        acc += mag * (q.z * __cosf(th) - q.w * __sinf(th));
    }
    Kt[t] = 2.0f * acc;
}

// ---------------- encoder GEMM: H0[M,256] = X[M,128]@W + b ----------------
__global__ __launch_bounds__(256) void k_enc(const float* __restrict__ X, const float* __restrict__ W,
                                             const float* __restrict__ bias, float* __restrict__ out) {
    __shared__ float As[128][33];
    __shared__ float Bs[32][128];
    int m0 = blockIdx.x * 128, n0 = blockIdx.y * 128;
    int tid = threadIdx.x;
    int tx = tid & 15, ty = tid >> 4;
    float acc[8][8] = {};
    for (int kt = 0; kt < DIN; kt += 32) {
#pragma unroll
        for (int i = 0; i < 16; ++i) {
            int e = tid + i * 256, kk = e & 31, mm = e >> 5;
            As[mm][kk] = X[(m0 + mm) * DIN + kt + kk];
        }
#pragma unroll
        for (int i = 0; i < 16; ++i) {
            int e = tid + i * 256, nn = e & 127, kk = e >> 7;
            Bs[kk][nn] = W[(kt + kk) * HDIM + n0 + nn];
        }
        __syncthreads();
#pragma unroll
        for (int kk = 0; kk < 32; ++kk) {
            float a[8], b[8];
#pragma unroll
            for (int i = 0; i < 8; ++i) a[i] = As[ty * 8 + i][kk];
#pragma unroll
            for (int j = 0; j < 8; ++j) b[j] = Bs[kk][tx * 8 + j];
#pragma unroll
            for (int i = 0; i < 8; ++i)
#pragma unroll
                for (int j = 0; j < 8; ++j) acc[i][j] = fmaf(a[i], b[j], acc[i][j]);
        }
        __syncthreads();
    }
#pragma unroll
    for (int i = 0; i < 8; ++i) {
        int m = m0 + ty * 8 + i;
#pragma unroll
        for (int j = 0; j < 8; ++j) {
            int n = n0 + tx * 8 + j;
            out[m * HDIM + n] = acc[i][j] + bias[n];
        }
    }
}

// ---------------- causal conv + D*u + GELU ----------------
// y[b,l,h] = gelu( sum_{d=0..l} K[h,d]*u[b,l-d,h] + D[h]*u[b,l,h] )
__global__ __launch_bounds__(256) void k_conv(const float* __restrict__ U, const float* __restrict__ Ktl,
                                              const float* __restrict__ Dw, float* __restrict__ Yout) {
    __shared__ float Ks[64][64];    // [d][h]
    __shared__ float Us[128][64];   // [window][h]
    int l0 = blockIdx.x * 64, h0 = blockIdx.y * 64, b = blockIdx.z;
    int tid = threadIdx.x, hh = tid & 63, lg = tid >> 6;
    int lb = l0 + lg * 16;
    float acc[16] = {};
    for (int dt0 = 0; dt0 <= l0; dt0 += 64) {
        int u0 = l0 - dt0 - 63;
#pragma unroll
        for (int i = 0; i < 16; ++i) {   // 64 rows of K tile
            int r = lg + 4 * i;
            Ks[r][hh] = Ktl[(dt0 + r) * HDIM + h0 + hh];
        }
#pragma unroll
        for (int i = 0; i < 32; ++i) {   // 128-row u window (zero-filled => causality)
            int r = lg + 4 * i;
            int gl = u0 + r;
            Us[r][hh] = (gl >= 0 && gl < LSEQ) ? U[(b * LSEQ + gl) * HDIM + h0 + hh] : 0.0f;
        }
        __syncthreads();
        float uw[16];                    // register ring buffer of u window
        int base = lg * 16 + 63;
#pragma unroll
        for (int k2 = 0; k2 < 16; ++k2) uw[(63 + k2) & 15] = Us[base + k2][hh];
#pragma unroll
        for (int dd = 0; dd < 64; ++dd) {
            float kv = Ks[dd][hh];
#pragma unroll
            for (int ii = 0; ii < 16; ++ii)
                acc[ii] = fmaf(kv, uw[(63 + ii - dd) & 15], acc[ii]);
            if (dd < 63) uw[(62 - dd) & 15] = Us[base - 1 - dd][hh];
        }
        __syncthreads();
    }
    float Dv = Dw[h0 + hh];
#pragma unroll
    for (int ii = 0; ii < 16; ++ii) {
        int l = lb + ii;
        float uval = U[(b * LSEQ + l) * HDIM + h0 + hh];
        float v = acc[ii] + Dv * uval;
        float t = tanhf(0.7978845608028654f * (v + 0.044715f * v * v * v));
        Yout[(b * LSEQ + l) * HDIM + h0 + hh] = 0.5f * v * (1.0f + t);
    }
}

// ---------------- output GEMM + fused GLU ----------------
// z1 = Y@W[:, n], z2 = Y@W[:, n+256];  G = (z1+b1)*sigmoid(z2+b2)
__global__ __launch_bounds__(256) void k_glu(const float* __restrict__ Y, const float* __restrict__ W,
                                             const float* __restrict__ wb, float* __restrict__ G) {
    __shared__ float As[128][33];
    __shared__ float B1[32][128];
    __shared__ float B2[32][128];
    int m0 = blockIdx.x * 128, n0 = blockIdx.y * 128;
    int tid = threadIdx.x;
    int tx = tid & 15, ty = tid >> 4;
    float acc1[8][8] = {}, acc2[8][8] = {};
    for (int kt = 0; kt < HDIM; kt += 32) {
#pragma unroll
        for (int i = 0; i < 16; ++i) {
            int e = tid + i * 256, kk = e & 31, mm = e >> 5;
            As[mm][kk] = Y[(m0 + mm) * HDIM + kt + kk];
        }
#pragma unroll
        for (int i = 0; i < 16; ++i) {
            int e = tid + i * 256, nn = e & 127, kk = e >> 7;
            B1[kk][nn] = W[(kt + kk) * (2 * HDIM) + n0 + nn];
            B2[kk][nn] = W[(kt + kk) * (2 * HDIM) + HDIM + n0 + nn];
        }
        __syncthreads();
#pragma unroll
        for (int kk = 0; kk < 32; ++kk) {
            float a[8], b1[8], b2[8];
#pragma unroll
            for (int i = 0; i < 8; ++i) a[i] = As[ty * 8 + i][kk];
#pragma unroll
            for (int j = 0; j < 8; ++j) { b1[j] = B1[kk][tx * 8 + j]; b2[j] = B2[kk][tx * 8 + j]; }
#pragma unroll
            for (int i = 0; i < 8; ++i)
#pragma unroll
                for (int j = 0; j < 8; ++j) {
                    acc1[i][j] = fmaf(a[i], b1[j], acc1[i][j]);
                    acc2[i][j] = fmaf(a[i], b2[j], acc2[i][j]);
                }
        }
        __syncthreads();
    }
#pragma unroll
    for (int i = 0; i < 8; ++i) {
        int m = m0 + ty * 8 + i;
#pragma unroll
        for (int j = 0; j < 8; ++j) {
            int n = n0 + tx * 8 + j;
            float z1 = acc1[i][j] + wb[n];
            float z2 = acc2[i][j] + wb[HDIM + n];
            G[m * HDIM + n] = z1 / (1.0f + __expf(-z2));
        }
    }
}

// ---------------- residual + LayerNorm (in place on H) ----------------
__global__ void k_ln(const float* __restrict__ G, float* __restrict__ Hb,
                     const float* __restrict__ w, const float* __restrict__ bb) {
    int row = blockIdx.x, hh = threadIdx.x;
    float r = G[row * HDIM + hh] + Hb[row * HDIM + hh];
    float s = r;
#pragma unroll
    for (int m = 1; m < 64; m <<= 1) s += __shfl_xor(s, m, 64);
    __shared__ float red[8];
    int wv = hh >> 6, lane = hh & 63;
    if (lane == 0) red[wv] = s;
    __syncthreads();
    float mean = (red[0] + red[1] + red[2] + red[3]) * (1.0f / HDIM);
    float d = r - mean;
    float s2 = d * d;
#pragma unroll
    for (int m = 1; m < 64; m <<= 1) s2 += __shfl_xor(s2, m, 64);
    if (lane == 0) red[4 + wv] = s2;
    __syncthreads();
    float var = (red[4] + red[5] + red[6] + red[7]) * (1.0f / HDIM);
    float rstd = rsqrtf(var + 1e-5f);
    Hb[row * HDIM + hh] = d * rstd * w[hh] + bb[hh];
}

// ---------------- decoder ----------------
__global__ void k_dec(const float* __restrict__ Hb, const float* __restrict__ dw,
                      const float* __restrict__ db, float* __restrict__ out) {
    __shared__ float ws[HDIM * DOUT];
    int tid = threadIdx.x;                    // 320 threads
    for (int e = tid; e < HDIM * DOUT; e += 320) ws[e] = dw[e];
    __syncthreads();
    int r = tid / DOUT, o = tid - r * DOUT;
    int row = blockIdx.x * 32 + r;
    float acc = db[o];
    const float* hp = Hb + row * HDIM;
#pragma unroll 8
    for (int k = 0; k < HDIM; ++k) acc = fmaf(hp[k], ws[k * DOUT + o], acc);
    out[row * DOUT + o] = acc;
}

extern "C" void kernel_launch(void* const* d_in, const int* in_sizes, int n_in,
                              void* d_out, int out_size, void* d_ws, size_t ws_size,
                              hipStream_t stream) {
    const float* x        = (const float*)d_in[0];
    const float* enc_w    = (const float*)d_in[1];
    const float* enc_b    = (const float*)d_in[2];
    const float* log_dt   = (const float*)d_in[3];
    const float* A_re_log = (const float*)d_in[4];
    const float* A_im     = (const float*)d_in[5];
    const float* B_re     = (const float*)d_in[6];
    const float* B_im     = (const float*)d_in[7];
    const float* C_re     = (const float*)d_in[8];
    const float* C_im     = (const float*)d_in[9];
    const float* Dp       = (const float*)d_in[10];
    const float* ln_w     = (const float*)d_in[11];
    const float* ln_b     = (const float*)d_in[12];
    const float* out_w    = (const float*)d_in[13];
    const float* out_b    = (const float*)d_in[14];
    const float* dec_w    = (const float*)d_in[15];
    const float* dec_b    = (const float*)d_in[16];
    float* outp = (float*)d_out;

    float* w = (float*)d_ws;
    float4* PW  = (float4*)w;                                   // 32768 float4 = 512 KB
    float* Kt   = w + 4 * NLAYERS * HDIM * NSTATE;              // 4*1024*256 floats = 4 MB
    float* Hbuf = Kt + NLAYERS * LSEQ * HDIM;                   // 33.5 MB
    float* Ybuf = Hbuf + (size_t)M_ROWS * HDIM;                 // 33.5 MB
    float* Gbuf = Ybuf + (size_t)M_ROWS * HDIM;                 // 33.5 MB  (total ~105 MB)

    k_params<<<NLAYERS * HDIM * NSTATE / 256, 256, 0, stream>>>(log_dt, A_re_log, A_im,
                                                                B_re, B_im, C_re, C_im, PW);
    k_kern<<<NLAYERS * LSEQ * HDIM / 256, 256, 0, stream>>>(PW, Kt);

    dim3 ge(M_ROWS / 128, HDIM / 128);
    k_enc<<<ge, 256, 0, stream>>>(x, enc_w, enc_b, Hbuf);

    for (int layer = 0; layer < NLAYERS; ++layer) {
        dim3 gc(LSEQ / 64, HDIM / 64, B_SZ);
        k_conv<<<gc, 256, 0, stream>>>(Hbuf, Kt + (size_t)layer * LSEQ * HDIM,
                                       Dp + layer * HDIM, Ybuf);
        dim3 gg(M_ROWS / 128, HDIM / 128);
        k_glu<<<gg, 256, 0, stream>>>(Ybuf, out_w + (size_t)layer * HDIM * 2 * HDIM,
                                      out_b + layer * 2 * HDIM, Gbuf);
        k_ln<<<M_ROWS, HDIM, 0, stream>>>(Gbuf, Hbuf, ln_w + layer * HDIM, ln_b + layer * HDIM);
    }
    k_dec<<<M_ROWS / 32, 320, 0, stream>>>(Hbuf, dec_w, dec_b, outp);
}

// Round 3
// 1801.361 us; speedup vs baseline: 1.5715x; 1.5715x over previous
//
#include <hip/hip_runtime.h>
#include <hip/hip_bf16.h>
#include <math.h>

#define B_SZ    32
#define LSEQ    1024
#define DIN     128
#define HDIM    256
#define NLAYERS 4
#define NSTATE  32
#define DOUT    10
#define M_ROWS  (B_SZ*LSEQ)   // 32768
#define CHUNK   128

// ---------------- per-(layer,h,n) discretized params ----------------
// PW[idx] = (dA_re, dA_im, W_re, W_im) where dA = exp(dt*A), W = C * dB
__global__ void k_params(const float* __restrict__ log_dt, const float* __restrict__ A_re_log,
                         const float* __restrict__ A_im, const float* __restrict__ B_re,
                         const float* __restrict__ B_im, const float* __restrict__ C_re,
                         const float* __restrict__ C_im, float4* __restrict__ PW) {
    int idx = blockIdx.x * 256 + threadIdx.x;       // [0, NLAYERS*HDIM*NSTATE)
    int hn = idx >> 5;                              // layer*HDIM + h
    float dt   = expf(log_dt[hn]);
    float Are  = -expf(A_re_log[idx]);
    float Aim  = A_im[idx];
    float dtAre = dt * Are, dtAim = dt * Aim;
    float ea   = expf(dtAre);
    float dAre = ea * cosf(dtAim), dAim = ea * sinf(dtAim);
    float nre = dAre - 1.0f, nim = dAim;            // dA - 1
    float inv = 1.0f / (Are * Are + Aim * Aim);
    float tre = (nre * Are + nim * Aim) * inv;      // (dA-1)/A
    float tim = (nim * Are - nre * Aim) * inv;
    float Brv = B_re[idx], Biv = B_im[idx];
    float dBre = Brv * tre - Biv * tim;
    float dBim = Brv * tim + Biv * tre;
    float Crv = C_re[idx], Civ = C_im[idx];
    float Wre = Crv * dBre - Civ * dBim;
    float Wim = Crv * dBim + Civ * dBre;
    PW[idx] = make_float4(dAre, dAim, Wre, Wim);
}

// ---------------- fused S4D scan + D*u + GELU ----------------
// p_n[l] = dA_n p_n[l-1] + W_n u[l];  y[l] = gelu(2*Re(sum_n p_n[l]) + D*u[l])
// block: 256 threads = 32 modes x 8 channels; grid (HDIM/8, B)
__global__ __launch_bounds__(256) void k_scan(const float* __restrict__ U, const float4* __restrict__ PW,
                                              const float* __restrict__ Dw, float* __restrict__ Yout) {
    __shared__ float u_s[8][CHUNK + 8];   // stride 136: epilogue 2-way conflict (free)
    __shared__ float y_s[8][CHUNK + 8];
    __shared__ float d_s[8];
    int tid = threadIdx.x;
    int n = tid & 31, hs = tid >> 5;
    int h0 = blockIdx.x * 8, b = blockIdx.y;
    float4 pw = PW[(h0 + hs) * NSTATE + n];
    float dAre = pw.x, dAim = pw.y, Wre = pw.z, Wim = pw.w;
    if (tid < 8) d_s[tid] = Dw[h0 + tid];
    float pre = 0.f, pim = 0.f;
    const float* Ub = U + (size_t)b * LSEQ * HDIM + h0;
    float*       Yb = Yout + (size_t)b * LSEQ * HDIM + h0;

    for (int l0 = 0; l0 < LSEQ; l0 += CHUNK) {
#pragma unroll
        for (int i = 0; i < CHUNK * 8 / 256; ++i) {            // stage u chunk
            int e = tid + i * 256, row = e >> 3, hc = e & 7;
            u_s[hc][row] = Ub[(l0 + row) * HDIM + hc];
        }
        __syncthreads();
#pragma unroll
        for (int j = 0; j < CHUNK; j += 4) {
            float4 uv = *(const float4*)&u_s[hs][j];
            float u0 = uv.x, u1 = uv.y, u2 = uv.z, u3 = uv.w;
#define STEP(UU, JJ)                                                        \
            {                                                               \
                float npre = fmaf(dAre, pre, fmaf(-dAim, pim, Wre * (UU))); \
                float npim = fmaf(dAre, pim, fmaf(dAim, pre, Wim * (UU))); \
                pre = npre; pim = npim;                                     \
                float r = pre;                                              \
                r += __shfl_xor(r, 1);  r += __shfl_xor(r, 2);              \
                r += __shfl_xor(r, 4);  r += __shfl_xor(r, 8);              \
                r += __shfl_xor(r, 16);                                     \
                if (n == 0) y_s[hs][(JJ)] = r;                              \
            }
            STEP(u0, j + 0) STEP(u1, j + 1) STEP(u2, j + 2) STEP(u3, j + 3)
#undef STEP
        }
        __syncthreads();
#pragma unroll
        for (int i = 0; i < CHUNK * 8 / 256; ++i) {            // epilogue: D*u + gelu
            int e = tid + i * 256, row = e >> 3, hc = e & 7;
            float u = u_s[hc][row];
            float v = 2.0f * y_s[hc][row] + d_s[hc] * u;
            float t = tanhf(0.7978845608028654f * (v + 0.044715f * v * v * v));
            Yb[(l0 + row) * HDIM + hc] = 0.5f * v * (1.0f + t);
        }
        __syncthreads();
    }
}

// ---------------- encoder GEMM: H0[M,256] = X[M,128]@W + b ----------------
__global__ __launch_bounds__(256) void k_enc(const float* __restrict__ X, const float* __restrict__ W,
                                             const float* __restrict__ bias, float* __restrict__ out) {
    __shared__ float As[128][33];
    __shared__ float Bs[32][128];
    int m0 = blockIdx.x * 128, n0 = blockIdx.y * 128;
    int tid = threadIdx.x;
    int tx = tid & 15, ty = tid >> 4;
    float acc[8][8] = {};
    for (int kt = 0; kt < DIN; kt += 32) {
#pragma unroll
        for (int i = 0; i < 16; ++i) {
            int e = tid + i * 256, kk = e & 31, mm = e >> 5;
            As[mm][kk] = X[(m0 + mm) * DIN + kt + kk];
        }
#pragma unroll
        for (int i = 0; i < 16; ++i) {
            int e = tid + i * 256, nn = e & 127, kk = e >> 7;
            Bs[kk][nn] = W[(kt + kk) * HDIM + n0 + nn];
        }
        __syncthreads();
#pragma unroll
        for (int kk = 0; kk < 32; ++kk) {
            float a[8], b[8];
#pragma unroll
            for (int i = 0; i < 8; ++i) a[i] = As[ty * 8 + i][kk];
#pragma unroll
            for (int j = 0; j < 8; ++j) b[j] = Bs[kk][tx * 8 + j];
#pragma unroll
            for (int i = 0; i < 8; ++i)
#pragma unroll
                for (int j = 0; j < 8; ++j) acc[i][j] = fmaf(a[i], b[j], acc[i][j]);
        }
        __syncthreads();
    }
#pragma unroll
    for (int i = 0; i < 8; ++i) {
        int m = m0 + ty * 8 + i;
#pragma unroll
        for (int j = 0; j < 8; ++j) {
            int n = n0 + tx * 8 + j;
            out[m * HDIM + n] = acc[i][j] + bias[n];
        }
    }
}

// ---------------- output GEMM + fused GLU ----------------
__global__ __launch_bounds__(256) void k_glu(const float* __restrict__ Y, const float* __restrict__ W,
                                             const float* __restrict__ wb, float* __restrict__ G) {
    __shared__ float As[128][33];
    __shared__ float B1[32][128];
    __shared__ float B2[32][128];
    int m0 = blockIdx.x * 128, n0 = blockIdx.y * 128;
    int tid = threadIdx.x;
    int tx = tid & 15, ty = tid >> 4;
    float acc1[8][8] = {}, acc2[8][8] = {};
    for (int kt = 0; kt < HDIM; kt += 32) {
#pragma unroll
        for (int i = 0; i < 16; ++i) {
            int e = tid + i * 256, kk = e & 31, mm = e >> 5;
            As[mm][kk] = Y[(m0 + mm) * HDIM + kt + kk];
        }
#pragma unroll
        for (int i = 0; i < 16; ++i) {
            int e = tid + i * 256, nn = e & 127, kk = e >> 7;
            B1[kk][nn] = W[(kt + kk) * (2 * HDIM) + n0 + nn];
            B2[kk][nn] = W[(kt + kk) * (2 * HDIM) + HDIM + n0 + nn];
        }
        __syncthreads();
#pragma unroll
        for (int kk = 0; kk < 32; ++kk) {
            float a[8], b1[8], b2[8];
#pragma unroll
            for (int i = 0; i < 8; ++i) a[i] = As[ty * 8 + i][kk];
#pragma unroll
            for (int j = 0; j < 8; ++j) { b1[j] = B1[kk][tx * 8 + j]; b2[j] = B2[kk][tx * 8 + j]; }
#pragma unroll
            for (int i = 0; i < 8; ++i)
#pragma unroll
                for (int j = 0; j < 8; ++j) {
                    acc1[i][j] = fmaf(a[i], b1[j], acc1[i][j]);
                    acc2[i][j] = fmaf(a[i], b2[j], acc2[i][j]);
                }
        }
        __syncthreads();
    }
#pragma unroll
    for (int i = 0; i < 8; ++i) {
        int m = m0 + ty * 8 + i;
#pragma unroll
        for (int j = 0; j < 8; ++j) {
            int n = n0 + tx * 8 + j;
            float z1 = acc1[i][j] + wb[n];
            float z2 = acc2[i][j] + wb[HDIM + n];
            G[m * HDIM + n] = z1 / (1.0f + __expf(-z2));
        }
    }
}

// ---------------- residual + LayerNorm (in place on H) ----------------
__global__ void k_ln(const float* __restrict__ G, float* __restrict__ Hb,
                     const float* __restrict__ w, const float* __restrict__ bb) {
    int row = blockIdx.x, hh = threadIdx.x;
    float r = G[row * HDIM + hh] + Hb[row * HDIM + hh];
    float s = r;
#pragma unroll
    for (int m = 1; m < 64; m <<= 1) s += __shfl_xor(s, m, 64);
    __shared__ float red[8];
    int wv = hh >> 6, lane = hh & 63;
    if (lane == 0) red[wv] = s;
    __syncthreads();
    float mean = (red[0] + red[1] + red[2] + red[3]) * (1.0f / HDIM);
    float d = r - mean;
    float s2 = d * d;
#pragma unroll
    for (int m = 1; m < 64; m <<= 1) s2 += __shfl_xor(s2, m, 64);
    if (lane == 0) red[4 + wv] = s2;
    __syncthreads();
    float var = (red[4] + red[5] + red[6] + red[7]) * (1.0f / HDIM);
    float rstd = rsqrtf(var + 1e-5f);
    Hb[row * HDIM + hh] = d * rstd * w[hh] + bb[hh];
}

// ---------------- decoder ----------------
__global__ void k_dec(const float* __restrict__ Hb, const float* __restrict__ dw,
                      const float* __restrict__ db, float* __restrict__ out) {
    __shared__ float ws[HDIM * DOUT];
    int tid = threadIdx.x;                    // 320 threads
    for (int e = tid; e < HDIM * DOUT; e += 320) ws[e] = dw[e];
    __syncthreads();
    int r = tid / DOUT, o = tid - r * DOUT;
    int row = blockIdx.x * 32 + r;
    float acc = db[o];
    const float* hp = Hb + row * HDIM;
#pragma unroll 8
    for (int k = 0; k < HDIM; ++k) acc = fmaf(hp[k], ws[k * DOUT + o], acc);
    out[row * DOUT + o] = acc;
}

extern "C" void kernel_launch(void* const* d_in, const int* in_sizes, int n_in,
                              void* d_out, int out_size, void* d_ws, size_t ws_size,
                              hipStream_t stream) {
    const float* x        = (const float*)d_in[0];
    const float* enc_w    = (const float*)d_in[1];
    const float* enc_b    = (const float*)d_in[2];
    const float* log_dt   = (const float*)d_in[3];
    const float* A_re_log = (const float*)d_in[4];
    const float* A_im     = (const float*)d_in[5];
    const float* B_re     = (const float*)d_in[6];
    const float* B_im     = (const float*)d_in[7];
    const float* C_re     = (const float*)d_in[8];
    const float* C_im     = (const float*)d_in[9];
    const float* Dp       = (const float*)d_in[10];
    const float* ln_w     = (const float*)d_in[11];
    const float* ln_b     = (const float*)d_in[12];
    const float* out_w    = (const float*)d_in[13];
    const float* out_b    = (const float*)d_in[14];
    const float* dec_w    = (const float*)d_in[15];
    const float* dec_b    = (const float*)d_in[16];
    float* outp = (float*)d_out;

    float* w = (float*)d_ws;
    float4* PW  = (float4*)w;                                   // 32768 float4 = 512 KB
    float* Hbuf = w + 4 * NLAYERS * HDIM * NSTATE;              // 33.5 MB
    float* Ybuf = Hbuf + (size_t)M_ROWS * HDIM;                 // 33.5 MB
    float* Gbuf = Ybuf + (size_t)M_ROWS * HDIM;                 // 33.5 MB  (total ~101 MB)

    k_params<<<NLAYERS * HDIM * NSTATE / 256, 256, 0, stream>>>(log_dt, A_re_log, A_im,
                                                                B_re, B_im, C_re, C_im, PW);

    dim3 ge(M_ROWS / 128, HDIM / 128);
    k_enc<<<ge, 256, 0, stream>>>(x, enc_w, enc_b, Hbuf);

    for (int layer = 0; layer < NLAYERS; ++layer) {
        dim3 gs(HDIM / 8, B_SZ);
        k_scan<<<gs, 256, 0, stream>>>(Hbuf, PW + (size_t)layer * HDIM * NSTATE,
                                       Dp + layer * HDIM, Ybuf);
        dim3 gg(M_ROWS / 128, HDIM / 128);
        k_glu<<<gg, 256, 0, stream>>>(Ybuf, out_w + (size_t)layer * HDIM * 2 * HDIM,
                                      out_b + layer * 2 * HDIM, Gbuf);
        k_ln<<<M_ROWS, HDIM, 0, stream>>>(Gbuf, Hbuf, ln_w + layer * HDIM, ln_b + layer * HDIM);
    }
    k_dec<<<M_ROWS / 32, 320, 0, stream>>>(Hbuf, dec_w, dec_b, outp);
}

// Round 4
// 1330.232 us; speedup vs baseline: 2.1280x; 1.3542x over previous
//
#include <hip/hip_runtime.h>
#include <hip/hip_bf16.h>
#include <math.h>

#define B_SZ    32
#define LSEQ    1024
#define DIN     128
#define HDIM    256
#define NLAYERS 4
#define NSTATE  32
#define DOUT    10
#define M_ROWS  (B_SZ*LSEQ)   // 32768
#define CH      64            // scan chunk length
#define NCH     (LSEQ/CH)     // 16 chunks

// ---------------- per-(layer,h,n) discretized params ----------------
// PWt[(layer*32+n)*256+h] = (dA_re, dA_im, W_re, W_im);  PA64 = dA^64 (complex)
__global__ void k_params(const float* __restrict__ log_dt, const float* __restrict__ A_re_log,
                         const float* __restrict__ A_im, const float* __restrict__ B_re,
                         const float* __restrict__ B_im, const float* __restrict__ C_re,
                         const float* __restrict__ C_im, float4* __restrict__ PWt,
                         float2* __restrict__ PA64) {
    int idx = blockIdx.x * 256 + threadIdx.x;       // layer*H*N + h*N + n
    int n = idx & 31, hn = idx >> 5;
    int h = hn & 255, layer = hn >> 8;
    float dt   = expf(log_dt[hn]);
    float Are  = -expf(A_re_log[idx]);
    float Aim  = A_im[idx];
    float dtAre = dt * Are, dtAim = dt * Aim;
    float ea   = expf(dtAre);
    float dAre = ea * cosf(dtAim), dAim = ea * sinf(dtAim);
    float nre = dAre - 1.0f, nim = dAim;            // dA - 1
    float inv = 1.0f / (Are * Are + Aim * Aim);
    float tre = (nre * Are + nim * Aim) * inv;      // (dA-1)/A
    float tim = (nim * Are - nre * Aim) * inv;
    float Brv = B_re[idx], Biv = B_im[idx];
    float dBre = Brv * tre - Biv * tim;
    float dBim = Brv * tim + Biv * tre;
    float Crv = C_re[idx], Civ = C_im[idx];
    float Wre = Crv * dBre - Civ * dBim;
    float Wim = Crv * dBim + Civ * dBre;
    int o = (layer * NSTATE + n) * HDIM + h;
    PWt[o] = make_float4(dAre, dAim, Wre, Wim);
    float e64 = expf(64.0f * dtAre);
    float ph  = 64.0f * dtAim;
    PA64[o] = make_float2(e64 * cosf(ph), e64 * sinf(ph));
}

// ---------------- scan phase A: chunk-end states ----------------
// E[((b*NCH+c)*NSTATE+n)*HDIM+h] = sum_{j<CH} dA^(CH-1-j) W u[cCH+j]
__global__ __launch_bounds__(256) void k_scanA(const float* __restrict__ U,
                                               const float4* __restrict__ PWt,
                                               float2* __restrict__ E) {
    int c = blockIdx.x, b = blockIdx.y, h = threadIdx.x;
    const float* Ub = U + ((size_t)b * LSEQ + c * CH) * HDIM + h;
    for (int t = 0; t < 4; ++t) {                  // 4 mode-tiles of 8
        float4 pw[8];
#pragma unroll
        for (int i = 0; i < 8; ++i) pw[i] = PWt[(t * 8 + i) * HDIM + h];
        float sre[8] = {}, sim[8] = {};
        for (int j = 0; j < CH; j += 4) {
            float u0 = Ub[(j + 0) * HDIM], u1 = Ub[(j + 1) * HDIM];
            float u2 = Ub[(j + 2) * HDIM], u3 = Ub[(j + 3) * HDIM];
#define ASTEP(UU)                                                               \
            _Pragma("unroll")                                                   \
            for (int i = 0; i < 8; ++i) {                                       \
                float nr = fmaf(pw[i].x, sre[i], fmaf(-pw[i].y, sim[i], pw[i].z * (UU))); \
                sim[i]   = fmaf(pw[i].x, sim[i], fmaf( pw[i].y, sre[i], pw[i].w * (UU))); \
                sre[i] = nr;                                                    \
            }
            ASTEP(u0) ASTEP(u1) ASTEP(u2) ASTEP(u3)
#undef ASTEP
        }
#pragma unroll
        for (int i = 0; i < 8; ++i)
            E[((size_t)(b * NCH + c) * NSTATE + t * 8 + i) * HDIM + h] = make_float2(sre[i], sim[i]);
    }
}

// ---------------- scan phase B: carry scan over chunks (in place) ----------------
// after: E[c] holds carry_c = state entering chunk c
__global__ void k_scanB(float2* __restrict__ E, const float2* __restrict__ PA64) {
    int n = blockIdx.x, b = blockIdx.y, h = threadIdx.x;
    float2 a = PA64[n * HDIM + h];
    float cr = 0.f, ci = 0.f;
    for (int c = 0; c < NCH; ++c) {
        size_t off = ((size_t)(b * NCH + c) * NSTATE + n) * HDIM + h;
        float2 e = E[off];
        E[off] = make_float2(cr, ci);
        float nr = fmaf(a.x, cr, fmaf(-a.y, ci, e.x));
        ci = fmaf(a.x, ci, fmaf(a.y, cr, e.y));
        cr = nr;
    }
}

// ---------------- scan phase C: seeded re-scan + D*u + GELU ----------------
__global__ __launch_bounds__(256) void k_scanC(const float* __restrict__ U,
                                               const float4* __restrict__ PWt,
                                               const float2* __restrict__ E,
                                               const float* __restrict__ Dw,
                                               float* __restrict__ Yout) {
    __shared__ float y_s[CH][HDIM];                // private column per thread, conflict-free
    int c = blockIdx.x, b = blockIdx.y, h = threadIdx.x;
    const float* Ub = U + ((size_t)b * LSEQ + c * CH) * HDIM + h;
    float*       Yb = Yout + ((size_t)b * LSEQ + c * CH) * HDIM + h;
    for (int t = 0; t < 4; ++t) {
        float4 pw[8];
        float sre[8], sim[8];
#pragma unroll
        for (int i = 0; i < 8; ++i) {
            pw[i] = PWt[(t * 8 + i) * HDIM + h];
            float2 e = E[((size_t)(b * NCH + c) * NSTATE + t * 8 + i) * HDIM + h];
            sre[i] = e.x; sim[i] = e.y;
        }
        for (int j = 0; j < CH; j += 4) {
            float u0 = Ub[(j + 0) * HDIM], u1 = Ub[(j + 1) * HDIM];
            float u2 = Ub[(j + 2) * HDIM], u3 = Ub[(j + 3) * HDIM];
#define CSTEP(UU, JJ)                                                           \
            {                                                                   \
                float s = 0.f;                                                  \
                _Pragma("unroll")                                               \
                for (int i = 0; i < 8; ++i) {                                   \
                    float nr = fmaf(pw[i].x, sre[i], fmaf(-pw[i].y, sim[i], pw[i].z * (UU))); \
                    sim[i]   = fmaf(pw[i].x, sim[i], fmaf( pw[i].y, sre[i], pw[i].w * (UU))); \
                    sre[i] = nr; s += nr;                                       \
                }                                                               \
                if (t == 0) y_s[(JJ)][h] = s; else y_s[(JJ)][h] += s;           \
            }
            CSTEP(u0, j + 0) CSTEP(u1, j + 1) CSTEP(u2, j + 2) CSTEP(u3, j + 3)
#undef CSTEP
        }
    }
    float Dv = Dw[h];
    for (int j = 0; j < CH; ++j) {
        float u = Ub[j * HDIM];
        float v = 2.0f * y_s[j][h] + Dv * u;
        float tt = tanhf(0.7978845608028654f * (v + 0.044715f * v * v * v));
        Yb[j * HDIM] = 0.5f * v * (1.0f + tt);
    }
}

// ---------------- encoder GEMM: H0[M,256] = X[M,128]@W + b ----------------
__global__ __launch_bounds__(256) void k_enc(const float* __restrict__ X, const float* __restrict__ W,
                                             const float* __restrict__ bias, float* __restrict__ out) {
    __shared__ float As[128][33];
    __shared__ float Bs[32][128];
    int m0 = blockIdx.x * 128, n0 = blockIdx.y * 128;
    int tid = threadIdx.x;
    int tx = tid & 15, ty = tid >> 4;
    float acc[8][8] = {};
    for (int kt = 0; kt < DIN; kt += 32) {
#pragma unroll
        for (int i = 0; i < 16; ++i) {
            int e = tid + i * 256, kk = e & 31, mm = e >> 5;
            As[mm][kk] = X[(m0 + mm) * DIN + kt + kk];
        }
#pragma unroll
        for (int i = 0; i < 16; ++i) {
            int e = tid + i * 256, nn = e & 127, kk = e >> 7;
            Bs[kk][nn] = W[(kt + kk) * HDIM + n0 + nn];
        }
        __syncthreads();
#pragma unroll
        for (int kk = 0; kk < 32; ++kk) {
            float a[8], b[8];
#pragma unroll
            for (int i = 0; i < 8; ++i) a[i] = As[ty * 8 + i][kk];
#pragma unroll
            for (int j = 0; j < 8; ++j) b[j] = Bs[kk][tx * 8 + j];
#pragma unroll
            for (int i = 0; i < 8; ++i)
#pragma unroll
                for (int j = 0; j < 8; ++j) acc[i][j] = fmaf(a[i], b[j], acc[i][j]);
        }
        __syncthreads();
    }
#pragma unroll
    for (int i = 0; i < 8; ++i) {
        int m = m0 + ty * 8 + i;
#pragma unroll
        for (int j = 0; j < 8; ++j) {
            int n = n0 + tx * 8 + j;
            out[m * HDIM + n] = acc[i][j] + bias[n];
        }
    }
}

// ---------------- output GEMM + fused GLU ----------------
__global__ __launch_bounds__(256) void k_glu(const float* __restrict__ Y, const float* __restrict__ W,
                                             const float* __restrict__ wb, float* __restrict__ G) {
    __shared__ float As[128][33];
    __shared__ float B1[32][128];
    __shared__ float B2[32][128];
    int m0 = blockIdx.x * 128, n0 = blockIdx.y * 128;
    int tid = threadIdx.x;
    int tx = tid & 15, ty = tid >> 4;
    float acc1[8][8] = {}, acc2[8][8] = {};
    for (int kt = 0; kt < HDIM; kt += 32) {
#pragma unroll
        for (int i = 0; i < 16; ++i) {
            int e = tid + i * 256, kk = e & 31, mm = e >> 5;
            As[mm][kk] = Y[(m0 + mm) * HDIM + kt + kk];
        }
#pragma unroll
        for (int i = 0; i < 16; ++i) {
            int e = tid + i * 256, nn = e & 127, kk = e >> 7;
            B1[kk][nn] = W[(kt + kk) * (2 * HDIM) + n0 + nn];
            B2[kk][nn] = W[(kt + kk) * (2 * HDIM) + HDIM + n0 + nn];
        }
        __syncthreads();
#pragma unroll
        for (int kk = 0; kk < 32; ++kk) {
            float a[8], b1[8], b2[8];
#pragma unroll
            for (int i = 0; i < 8; ++i) a[i] = As[ty * 8 + i][kk];
#pragma unroll
            for (int j = 0; j < 8; ++j) { b1[j] = B1[kk][tx * 8 + j]; b2[j] = B2[kk][tx * 8 + j]; }
#pragma unroll
            for (int i = 0; i < 8; ++i)
#pragma unroll
                for (int j = 0; j < 8; ++j) {
                    acc1[i][j] = fmaf(a[i], b1[j], acc1[i][j]);
                    acc2[i][j] = fmaf(a[i], b2[j], acc2[i][j]);
                }
        }
        __syncthreads();
    }
#pragma unroll
    for (int i = 0; i < 8; ++i) {
        int m = m0 + ty * 8 + i;
#pragma unroll
        for (int j = 0; j < 8; ++j) {
            int n = n0 + tx * 8 + j;
            float z1 = acc1[i][j] + wb[n];
            float z2 = acc2[i][j] + wb[HDIM + n];
            G[m * HDIM + n] = z1 / (1.0f + __expf(-z2));
        }
    }
}

// ---------------- residual + LayerNorm (in place on H) ----------------
__global__ void k_ln(const float* __restrict__ G, float* __restrict__ Hb,
                     const float* __restrict__ w, const float* __restrict__ bb) {
    int row = blockIdx.x, hh = threadIdx.x;
    float r = G[row * HDIM + hh] + Hb[row * HDIM + hh];
    float s = r;
#pragma unroll
    for (int m = 1; m < 64; m <<= 1) s += __shfl_xor(s, m, 64);
    __shared__ float red[8];
    int wv = hh >> 6, lane = hh & 63;
    if (lane == 0) red[wv] = s;
    __syncthreads();
    float mean = (red[0] + red[1] + red[2] + red[3]) * (1.0f / HDIM);
    float d = r - mean;
    float s2 = d * d;
#pragma unroll
    for (int m = 1; m < 64; m <<= 1) s2 += __shfl_xor(s2, m, 64);
    if (lane == 0) red[4 + wv] = s2;
    __syncthreads();
    float var = (red[4] + red[5] + red[6] + red[7]) * (1.0f / HDIM);
    float rstd = rsqrtf(var + 1e-5f);
    Hb[row * HDIM + hh] = d * rstd * w[hh] + bb[hh];
}

// ---------------- decoder ----------------
__global__ void k_dec(const float* __restrict__ Hb, const float* __restrict__ dw,
                      const float* __restrict__ db, float* __restrict__ out) {
    __shared__ float ws[HDIM * DOUT];
    int tid = threadIdx.x;                    // 320 threads
    for (int e = tid; e < HDIM * DOUT; e += 320) ws[e] = dw[e];
    __syncthreads();
    int r = tid / DOUT, o = tid - r * DOUT;
    int row = blockIdx.x * 32 + r;
    float acc = db[o];
    const float* hp = Hb + row * HDIM;
#pragma unroll 8
    for (int k = 0; k < HDIM; ++k) acc = fmaf(hp[k], ws[k * DOUT + o], acc);
    out[row * DOUT + o] = acc;
}

extern "C" void kernel_launch(void* const* d_in, const int* in_sizes, int n_in,
                              void* d_out, int out_size, void* d_ws, size_t ws_size,
                              hipStream_t stream) {
    const float* x        = (const float*)d_in[0];
    const float* enc_w    = (const float*)d_in[1];
    const float* enc_b    = (const float*)d_in[2];
    const float* log_dt   = (const float*)d_in[3];
    const float* A_re_log = (const float*)d_in[4];
    const float* A_im     = (const float*)d_in[5];
    const float* B_re     = (const float*)d_in[6];
    const float* B_im     = (const float*)d_in[7];
    const float* C_re     = (const float*)d_in[8];
    const float* C_im     = (const float*)d_in[9];
    const float* Dp       = (const float*)d_in[10];
    const float* ln_w     = (const float*)d_in[11];
    const float* ln_b     = (const float*)d_in[12];
    const float* out_w    = (const float*)d_in[13];
    const float* out_b    = (const float*)d_in[14];
    const float* dec_w    = (const float*)d_in[15];
    const float* dec_b    = (const float*)d_in[16];
    float* outp = (float*)d_out;

    float* w = (float*)d_ws;
    float4* PWt  = (float4*)w;                                  // 4*32*256 float4 = 512 KB
    float2* PA64 = (float2*)(w + 4 * NLAYERS * NSTATE * HDIM);  // 256 KB
    float* Hbuf = w + 6 * NLAYERS * NSTATE * HDIM;              // 33.5 MB
    float* Ybuf = Hbuf + (size_t)M_ROWS * HDIM;                 // 33.5 MB
    float* Gbuf = Ybuf + (size_t)M_ROWS * HDIM;                 // 33.5 MB, aliased with E
    float2* Ebuf = (float2*)Gbuf;       // E: B*NCH*NSTATE*HDIM f2 = 33.5 MB (dead when G live)

    k_params<<<NLAYERS * HDIM * NSTATE / 256, 256, 0, stream>>>(log_dt, A_re_log, A_im,
                                                                B_re, B_im, C_re, C_im, PWt, PA64);

    dim3 ge(M_ROWS / 128, HDIM / 128);
    k_enc<<<ge, 256, 0, stream>>>(x, enc_w, enc_b, Hbuf);

    for (int layer = 0; layer < NLAYERS; ++layer) {
        const float4* pwl = (const float4*)PWt + (size_t)layer * NSTATE * HDIM;
        const float2* pal = (const float2*)PA64 + (size_t)layer * NSTATE * HDIM;
        dim3 gac(NCH, B_SZ);
        k_scanA<<<gac, 256, 0, stream>>>(Hbuf, pwl, Ebuf);
        dim3 gb(NSTATE, B_SZ);
        k_scanB<<<gb, 256, 0, stream>>>(Ebuf, pal);
        k_scanC<<<gac, 256, 0, stream>>>(Hbuf, pwl, Ebuf, Dp + layer * HDIM, Ybuf);
        dim3 gg(M_ROWS / 128, HDIM / 128);
        k_glu<<<gg, 256, 0, stream>>>(Ybuf, out_w + (size_t)layer * HDIM * 2 * HDIM,
                                      out_b + layer * 2 * HDIM, Gbuf);
        k_ln<<<M_ROWS, HDIM, 0, stream>>>(Gbuf, Hbuf, ln_w + layer * HDIM, ln_b + layer * HDIM);
    }
    k_dec<<<M_ROWS / 32, 320, 0, stream>>>(Hbuf, dec_w, dec_b, outp);
}

// Round 5
// 918.404 us; speedup vs baseline: 3.0823x; 1.4484x over previous
//
#include <hip/hip_runtime.h>
#include <hip/hip_bf16.h>
#include <math.h>

#define B_SZ    32
#define LSEQ    1024
#define DIN     128
#define HDIM    256
#define NLAYERS 4
#define NSTATE  32
#define DOUT    10
#define M_ROWS  (B_SZ*LSEQ)   // 32768
#define CH      64            // scan chunk length
#define NCH     (LSEQ/CH)     // 16 chunks

typedef __hip_bfloat16 bf16;
typedef __attribute__((ext_vector_type(8))) short bf16x8;
typedef __attribute__((ext_vector_type(4))) float f32x4;

// ---------------- per-(layer,h,n) discretized params ----------------
__global__ void k_params(const float* __restrict__ log_dt, const float* __restrict__ A_re_log,
                         const float* __restrict__ A_im, const float* __restrict__ B_re,
                         const float* __restrict__ B_im, const float* __restrict__ C_re,
                         const float* __restrict__ C_im, float4* __restrict__ PWt,
                         float2* __restrict__ PA64) {
    int idx = blockIdx.x * 256 + threadIdx.x;       // layer*H*N + h*N + n
    int n = idx & 31, hn = idx >> 5;
    int h = hn & 255, layer = hn >> 8;
    float dt   = expf(log_dt[hn]);
    float Are  = -expf(A_re_log[idx]);
    float Aim  = A_im[idx];
    float dtAre = dt * Are, dtAim = dt * Aim;
    float ea   = expf(dtAre);
    float dAre = ea * cosf(dtAim), dAim = ea * sinf(dtAim);
    float nre = dAre - 1.0f, nim = dAim;            // dA - 1
    float inv = 1.0f / (Are * Are + Aim * Aim);
    float tre = (nre * Are + nim * Aim) * inv;      // (dA-1)/A
    float tim = (nim * Are - nre * Aim) * inv;
    float Brv = B_re[idx], Biv = B_im[idx];
    float dBre = Brv * tre - Biv * tim;
    float dBim = Brv * tim + Biv * tre;
    float Crv = C_re[idx], Civ = C_im[idx];
    float Wre = Crv * dBre - Civ * dBim;
    float Wim = Crv * dBim + Civ * dBre;
    int o = (layer * NSTATE + n) * HDIM + h;
    PWt[o] = make_float4(dAre, dAim, Wre, Wim);
    float e64 = expf(64.0f * dtAre);
    float ph  = 64.0f * dtAim;
    PA64[o] = make_float2(e64 * cosf(ph), e64 * sinf(ph));
}

// ---------------- one-off weight transpose+cast: Wt[layer][n(512)][k(256)] bf16 ----------------
__global__ void k_wcvt(const float* __restrict__ Wsrc, bf16* __restrict__ Wt) {
    int idx = blockIdx.x * 256 + threadIdx.x;   // ((layer*512)+n)*256+k
    int k = idx & 255;
    int n = (idx >> 8) & 511;
    int layer = idx >> 17;
    Wt[idx] = __float2bfloat16(Wsrc[((size_t)(layer * 256 + k)) * 512 + n]);
}

// ---------------- scan phase A: chunk-end states ----------------
__global__ __launch_bounds__(256) void k_scanA(const float* __restrict__ U,
                                               const float4* __restrict__ PWt,
                                               float2* __restrict__ E) {
    int c = blockIdx.x, b = blockIdx.y, h = threadIdx.x;
    const float* Ub = U + ((size_t)b * LSEQ + c * CH) * HDIM + h;
    for (int t = 0; t < 4; ++t) {                  // 4 mode-tiles of 8
        float4 pw[8];
#pragma unroll
        for (int i = 0; i < 8; ++i) pw[i] = PWt[(t * 8 + i) * HDIM + h];
        float sre[8] = {}, sim[8] = {};
        for (int j = 0; j < CH; j += 4) {
            float u0 = Ub[(j + 0) * HDIM], u1 = Ub[(j + 1) * HDIM];
            float u2 = Ub[(j + 2) * HDIM], u3 = Ub[(j + 3) * HDIM];
#define ASTEP(UU)                                                               \
            _Pragma("unroll")                                                   \
            for (int i = 0; i < 8; ++i) {                                       \
                float nr = fmaf(pw[i].x, sre[i], fmaf(-pw[i].y, sim[i], pw[i].z * (UU))); \
                sim[i]   = fmaf(pw[i].x, sim[i], fmaf( pw[i].y, sre[i], pw[i].w * (UU))); \
                sre[i] = nr;                                                    \
            }
            ASTEP(u0) ASTEP(u1) ASTEP(u2) ASTEP(u3)
#undef ASTEP
        }
#pragma unroll
        for (int i = 0; i < 8; ++i)
            E[((size_t)(b * NCH + c) * NSTATE + t * 8 + i) * HDIM + h] = make_float2(sre[i], sim[i]);
    }
}

// ---------------- scan phase B: carry scan over chunks (in place) ----------------
__global__ void k_scanB(float2* __restrict__ E, const float2* __restrict__ PA64) {
    int n = blockIdx.x, b = blockIdx.y, h = threadIdx.x;
    float2 a = PA64[n * HDIM + h];
    float cr = 0.f, ci = 0.f;
    for (int c = 0; c < NCH; ++c) {
        size_t off = ((size_t)(b * NCH + c) * NSTATE + n) * HDIM + h;
        float2 e = E[off];
        E[off] = make_float2(cr, ci);
        float nr = fmaf(a.x, cr, fmaf(-a.y, ci, e.x));
        ci = fmaf(a.x, ci, fmaf(a.y, cr, e.y));
        cr = nr;
    }
}

// ---------------- scan phase C: seeded re-scan + D*u + GELU -> bf16 Y ----------------
__global__ __launch_bounds__(256) void k_scanC(const float* __restrict__ U,
                                               const float4* __restrict__ PWt,
                                               const float2* __restrict__ E,
                                               const float* __restrict__ Dw,
                                               bf16* __restrict__ Yout) {
    __shared__ float y_s[CH][HDIM];                // private column per thread, conflict-free
    int c = blockIdx.x, b = blockIdx.y, h = threadIdx.x;
    const float* Ub = U + ((size_t)b * LSEQ + c * CH) * HDIM + h;
    bf16*        Yb = Yout + ((size_t)b * LSEQ + c * CH) * HDIM + h;
    for (int t = 0; t < 4; ++t) {
        float4 pw[8];
        float sre[8], sim[8];
#pragma unroll
        for (int i = 0; i < 8; ++i) {
            pw[i] = PWt[(t * 8 + i) * HDIM + h];
            float2 e = E[((size_t)(b * NCH + c) * NSTATE + t * 8 + i) * HDIM + h];
            sre[i] = e.x; sim[i] = e.y;
        }
        for (int j = 0; j < CH; j += 4) {
            float u0 = Ub[(j + 0) * HDIM], u1 = Ub[(j + 1) * HDIM];
            float u2 = Ub[(j + 2) * HDIM], u3 = Ub[(j + 3) * HDIM];
#define CSTEP(UU, JJ)                                                           \
            {                                                                   \
                float s = 0.f;                                                  \
                _Pragma("unroll")                                               \
                for (int i = 0; i < 8; ++i) {                                   \
                    float nr = fmaf(pw[i].x, sre[i], fmaf(-pw[i].y, sim[i], pw[i].z * (UU))); \
                    sim[i]   = fmaf(pw[i].x, sim[i], fmaf( pw[i].y, sre[i], pw[i].w * (UU))); \
                    sre[i] = nr; s += nr;                                       \
                }                                                               \
                if (t == 0) y_s[(JJ)][h] = s; else y_s[(JJ)][h] += s;           \
            }
            CSTEP(u0, j + 0) CSTEP(u1, j + 1) CSTEP(u2, j + 2) CSTEP(u3, j + 3)
#undef CSTEP
        }
    }
    float Dv = Dw[h];
    for (int j = 0; j < CH; ++j) {
        float u = Ub[j * HDIM];
        float v = 2.0f * y_s[j][h] + Dv * u;
        float tt = tanhf(0.7978845608028654f * (v + 0.044715f * v * v * v));
        Yb[j * HDIM] = __float2bfloat16(0.5f * v * (1.0f + tt));
    }
}

// ---------------- encoder GEMM: H0[M,256] = X[M,128]@W + b (fp32 vector) ----------------
__global__ __launch_bounds__(256) void k_enc(const float* __restrict__ X, const float* __restrict__ W,
                                             const float* __restrict__ bias, float* __restrict__ out) {
    __shared__ float As[128][33];
    __shared__ float Bs[32][128];
    int m0 = blockIdx.x * 128, n0 = blockIdx.y * 128;
    int tid = threadIdx.x;
    int tx = tid & 15, ty = tid >> 4;
    float acc[8][8] = {};
    for (int kt = 0; kt < DIN; kt += 32) {
#pragma unroll
        for (int i = 0; i < 16; ++i) {
            int e = tid + i * 256, kk = e & 31, mm = e >> 5;
            As[mm][kk] = X[(m0 + mm) * DIN + kt + kk];
        }
#pragma unroll
        for (int i = 0; i < 16; ++i) {
            int e = tid + i * 256, nn = e & 127, kk = e >> 7;
            Bs[kk][nn] = W[(kt + kk) * HDIM + n0 + nn];
        }
        __syncthreads();
#pragma unroll
        for (int kk = 0; kk < 32; ++kk) {
            float a[8], b[8];
#pragma unroll
            for (int i = 0; i < 8; ++i) a[i] = As[ty * 8 + i][kk];
#pragma unroll
            for (int j = 0; j < 8; ++j) b[j] = Bs[kk][tx * 8 + j];
#pragma unroll
            for (int i = 0; i < 8; ++i)
#pragma unroll
                for (int j = 0; j < 8; ++j) acc[i][j] = fmaf(a[i], b[j], acc[i][j]);
        }
        __syncthreads();
    }
#pragma unroll
    for (int i = 0; i < 8; ++i) {
        int m = m0 + ty * 8 + i;
#pragma unroll
        for (int j = 0; j < 8; ++j) {
            int n = n0 + tx * 8 + j;
            out[m * HDIM + n] = acc[i][j] + bias[n];
        }
    }
}

// ---------------- output GEMM + fused GLU, bf16 MFMA ----------------
// G[m,n] = (Y@W1 + b1) * sigmoid(Y@W2 + b2); W pre-transposed bf16: Wt[n(512)][k(256)]
// block 256 thr = 4 waves; tile 128m x 64n (z1 & z2); BK=64 staged LDS (pad stride 72)
__global__ __launch_bounds__(256) void k_glu(const bf16* __restrict__ Ybf,
                                             const bf16* __restrict__ Wt,
                                             const float* __restrict__ wb,
                                             float* __restrict__ G) {
    __shared__ short A_s[128 * 72];
    __shared__ short B1_s[64 * 72];
    __shared__ short B2_s[64 * 72];
    int tid = threadIdx.x;
    int lane = tid & 63, wv = tid >> 6;
    int quad = lane >> 4, fr = lane & 15;
    int m0 = blockIdx.x * 128, n0 = blockIdx.y * 64;
    f32x4 acc1[2][4] = {{{0.f,0.f,0.f,0.f}}};
    f32x4 acc2[2][4] = {{{0.f,0.f,0.f,0.f}}};
#pragma unroll
    for (int mt = 0; mt < 2; ++mt)
#pragma unroll
        for (int nt = 0; nt < 4; ++nt) {
            acc1[mt][nt] = (f32x4){0.f,0.f,0.f,0.f};
            acc2[mt][nt] = (f32x4){0.f,0.f,0.f,0.f};
        }
    for (int kt = 0; kt < HDIM; kt += 64) {
#pragma unroll
        for (int i = 0; i < 4; ++i) {            // A tile: 128 rows x 64 k
            int e = tid + i * 256, row = e >> 3, cm = e & 7;
            *(uint4*)&A_s[row * 72 + cm * 8] =
                *(const uint4*)(Ybf + (size_t)(m0 + row) * HDIM + kt + cm * 8);
        }
#pragma unroll
        for (int i = 0; i < 2; ++i) {            // B tiles: 64 n-rows x 64 k each
            int e = tid + i * 256, row = e >> 3, cm = e & 7;
            *(uint4*)&B1_s[row * 72 + cm * 8] =
                *(const uint4*)(Wt + (size_t)(n0 + row) * HDIM + kt + cm * 8);
            *(uint4*)&B2_s[row * 72 + cm * 8] =
                *(const uint4*)(Wt + (size_t)(256 + n0 + row) * HDIM + kt + cm * 8);
        }
        __syncthreads();
#pragma unroll
        for (int s = 0; s < 2; ++s) {            // two K=32 MFMA steps per stage
            bf16x8 a[2], b1[4], b2[4];
#pragma unroll
            for (int mt = 0; mt < 2; ++mt)
                a[mt] = *(const bf16x8*)&A_s[(wv * 32 + mt * 16 + fr) * 72 + s * 32 + quad * 8];
#pragma unroll
            for (int nt = 0; nt < 4; ++nt) {
                b1[nt] = *(const bf16x8*)&B1_s[(nt * 16 + fr) * 72 + s * 32 + quad * 8];
                b2[nt] = *(const bf16x8*)&B2_s[(nt * 16 + fr) * 72 + s * 32 + quad * 8];
            }
#pragma unroll
            for (int mt = 0; mt < 2; ++mt)
#pragma unroll
                for (int nt = 0; nt < 4; ++nt) {
                    acc1[mt][nt] = __builtin_amdgcn_mfma_f32_16x16x32_bf16(a[mt], b1[nt], acc1[mt][nt], 0, 0, 0);
                    acc2[mt][nt] = __builtin_amdgcn_mfma_f32_16x16x32_bf16(a[mt], b2[nt], acc2[mt][nt], 0, 0, 0);
                }
        }
        __syncthreads();
    }
    // epilogue: C/D layout col=lane&15, row=quad*4+reg  [m89-verified]
#pragma unroll
    for (int mt = 0; mt < 2; ++mt)
#pragma unroll
        for (int nt = 0; nt < 4; ++nt) {
            int n = n0 + nt * 16 + fr;
            float b1v = wb[n], b2v = wb[HDIM + n];
#pragma unroll
            for (int r = 0; r < 4; ++r) {
                int m = m0 + wv * 32 + mt * 16 + quad * 4 + r;
                float z1 = acc1[mt][nt][r] + b1v;
                float z2 = acc2[mt][nt][r] + b2v;
                G[(size_t)m * HDIM + n] = z1 / (1.0f + __expf(-z2));
            }
        }
}

// ---------------- residual + LayerNorm (in place on H) ----------------
__global__ void k_ln(const float* __restrict__ G, float* __restrict__ Hb,
                     const float* __restrict__ w, const float* __restrict__ bb) {
    int row = blockIdx.x, hh = threadIdx.x;
    float r = G[row * HDIM + hh] + Hb[row * HDIM + hh];
    float s = r;
#pragma unroll
    for (int m = 1; m < 64; m <<= 1) s += __shfl_xor(s, m, 64);
    __shared__ float red[8];
    int wv = hh >> 6, lane = hh & 63;
    if (lane == 0) red[wv] = s;
    __syncthreads();
    float mean = (red[0] + red[1] + red[2] + red[3]) * (1.0f / HDIM);
    float d = r - mean;
    float s2 = d * d;
#pragma unroll
    for (int m = 1; m < 64; m <<= 1) s2 += __shfl_xor(s2, m, 64);
    if (lane == 0) red[4 + wv] = s2;
    __syncthreads();
    float var = (red[4] + red[5] + red[6] + red[7]) * (1.0f / HDIM);
    float rstd = rsqrtf(var + 1e-5f);
    Hb[row * HDIM + hh] = d * rstd * w[hh] + bb[hh];
}

// ---------------- decoder ----------------
__global__ void k_dec(const float* __restrict__ Hb, const float* __restrict__ dw,
                      const float* __restrict__ db, float* __restrict__ out) {
    __shared__ float ws[HDIM * DOUT];
    int tid = threadIdx.x;                    // 320 threads
    for (int e = tid; e < HDIM * DOUT; e += 320) ws[e] = dw[e];
    __syncthreads();
    int r = tid / DOUT, o = tid - r * DOUT;
    int row = blockIdx.x * 32 + r;
    float acc = db[o];
    const float* hp = Hb + row * HDIM;
#pragma unroll 8
    for (int k = 0; k < HDIM; ++k) acc = fmaf(hp[k], ws[k * DOUT + o], acc);
    out[row * DOUT + o] = acc;
}

extern "C" void kernel_launch(void* const* d_in, const int* in_sizes, int n_in,
                              void* d_out, int out_size, void* d_ws, size_t ws_size,
                              hipStream_t stream) {
    const float* x        = (const float*)d_in[0];
    const float* enc_w    = (const float*)d_in[1];
    const float* enc_b    = (const float*)d_in[2];
    const float* log_dt   = (const float*)d_in[3];
    const float* A_re_log = (const float*)d_in[4];
    const float* A_im     = (const float*)d_in[5];
    const float* B_re     = (const float*)d_in[6];
    const float* B_im     = (const float*)d_in[7];
    const float* C_re     = (const float*)d_in[8];
    const float* C_im     = (const float*)d_in[9];
    const float* Dp       = (const float*)d_in[10];
    const float* ln_w     = (const float*)d_in[11];
    const float* ln_b     = (const float*)d_in[12];
    const float* out_w    = (const float*)d_in[13];
    const float* out_b    = (const float*)d_in[14];
    const float* dec_w    = (const float*)d_in[15];
    const float* dec_b    = (const float*)d_in[16];
    float* outp = (float*)d_out;

    float* w = (float*)d_ws;
    const size_t PWE = (size_t)NLAYERS * NSTATE * HDIM;         // 32768
    float4* PWt  = (float4*)w;                                  // 512 KB
    float2* PA64 = (float2*)(w + 4 * PWE);                      // 256 KB
    float* Hbuf = w + 6 * PWE;                                  // 33.5 MB
    float* Gbuf = Hbuf + (size_t)M_ROWS * HDIM;                 // 33.5 MB, aliased with E
    float2* Ebuf = (float2*)Gbuf;                               // dead when G live
    bf16* Ybf = (bf16*)(Gbuf + (size_t)M_ROWS * HDIM);          // 16.7 MB
    bf16* Wt  = Ybf + (size_t)M_ROWS * HDIM;                    // 1 MB

    k_params<<<NLAYERS * HDIM * NSTATE / 256, 256, 0, stream>>>(log_dt, A_re_log, A_im,
                                                                B_re, B_im, C_re, C_im, PWt, PA64);
    k_wcvt<<<NLAYERS * 512 * 256 / 256, 256, 0, stream>>>(out_w, Wt);

    dim3 ge(M_ROWS / 128, HDIM / 128);
    k_enc<<<ge, 256, 0, stream>>>(x, enc_w, enc_b, Hbuf);

    for (int layer = 0; layer < NLAYERS; ++layer) {
        const float4* pwl = (const float4*)PWt + (size_t)layer * NSTATE * HDIM;
        const float2* pal = (const float2*)PA64 + (size_t)layer * NSTATE * HDIM;
        dim3 gac(NCH, B_SZ);
        k_scanA<<<gac, 256, 0, stream>>>(Hbuf, pwl, Ebuf);
        dim3 gb(NSTATE, B_SZ);
        k_scanB<<<gb, 256, 0, stream>>>(Ebuf, pal);
        k_scanC<<<gac, 256, 0, stream>>>(Hbuf, pwl, Ebuf, Dp + layer * HDIM, Ybf);
        dim3 gg(M_ROWS / 128, HDIM / 64);
        k_glu<<<gg, 256, 0, stream>>>(Ybf, Wt + (size_t)layer * 512 * HDIM,
                                      out_b + layer * 2 * HDIM, Gbuf);
        k_ln<<<M_ROWS, HDIM, 0, stream>>>(Gbuf, Hbuf, ln_w + layer * HDIM, ln_b + layer * HDIM);
    }
    k_dec<<<M_ROWS / 32, 320, 0, stream>>>(Hbuf, dec_w, dec_b, outp);
}